// Round 6
// baseline (205.623 us; speedup 1.0000x reference)
//
#include <hip/hip_runtime.h>
#include <hip/hip_bf16.h>

typedef unsigned short u16;
typedef __bf16 bf16x8 __attribute__((ext_vector_type(8)));
typedef float floatx4 __attribute__((ext_vector_type(4)));

#define SB 4
#define ST 1024
#define SC 1024
#define SH 16
#define SD 64

__device__ __forceinline__ u16 f2bf(float f) {
    unsigned int u = __builtin_bit_cast(unsigned int, f);
    u += 0x7fffu + ((u >> 16) & 1u);   // RNE
    return (u16)(u >> 16);
}

// async 16B/lane global->LDS (m97). LDS dest is wave-uniform base + lane*16.
__device__ __forceinline__ void gload16(const u16* g, u16* l) {
    __builtin_amdgcn_global_load_lds(
        (const __attribute__((address_space(1))) unsigned int*)g,
        (__attribute__((address_space(3))) unsigned int*)l, 16, 0, 0);
}

// ---- fused prep: x->bf16 | Wq/Wk/Wv -> Wqkv[n][c] | Wp -> Wpt[n][k] ----
__global__ void k_prep(const float* __restrict__ x,
                       const float* __restrict__ Wq, const float* __restrict__ Wk,
                       const float* __restrict__ Wv, const float* __restrict__ Wp,
                       u16* __restrict__ xb, u16* __restrict__ Wqkv, u16* __restrict__ Wpt) {
    __shared__ float tile[64 * 65];
    const int id = blockIdx.x, tid = threadIdx.x;
    if (id < 4096) {                               // x: fp32 -> bf16, float4 lanes
        int i = id * 256 + tid;
        float4 v = ((const float4*)x)[i];
        uint2 o;
        o.x = (unsigned)f2bf(v.x) | ((unsigned)f2bf(v.y) << 16);
        o.y = (unsigned)f2bf(v.z) | ((unsigned)f2bf(v.w) << 16);
        ((uint2*)xb)[i] = o;
    } else if (id < 4864) {                        // Wq/Wk/Wv transpose to [n][c]
        const int id1 = id - 4096;
        const int qkv = id1 >> 8, rem = id1 & 255, h = rem >> 4, c0 = (rem & 15) * 64;
        const float* src = qkv == 0 ? Wq : (qkv == 1 ? Wk : Wv);
        #pragma unroll
        for (int i = 0; i < 16; ++i) {
            int idx = tid + i * 256;
            int r = idx >> 6, d = idx & 63;
            tile[r * 65 + d] = src[(h * SC + c0 + r) * SD + d];
        }
        __syncthreads();
        #pragma unroll
        for (int i = 0; i < 16; ++i) {
            int idx = tid + i * 256;
            int d = idx >> 6, cc = idx & 63;
            Wqkv[(qkv * 1024 + h * SD + d) * SC + c0 + cc] = f2bf(tile[cc * 65 + d]);
        }
    } else {                                       // Wp transpose to [n][k]
        const int id2 = id - 4864;
        const int n0 = (id2 & 15) * 64, k0 = (id2 >> 4) * 64;
        #pragma unroll
        for (int i = 0; i < 16; ++i) {
            int idx = tid + i * 256;
            int r = idx >> 6, nn = idx & 63;
            tile[r * 65 + nn] = Wp[(k0 + r) * SC + n0 + nn];
        }
        __syncthreads();
        #pragma unroll
        for (int i = 0; i < 16; ++i) {
            int idx = tid + i * 256;
            int nr = idx >> 6, kk = idx & 63;
            Wpt[(n0 + nr) * (SH * SD) + k0 + kk] = f2bf(tile[kk * 65 + nr]);
        }
    }
}

// ---- GEMM: C = A[M,K] * Bt[N,K]^T, bf16, BN=64, BK=64, BM templated ----
// Single-barrier prefetch double-buffer. Swapped-operand MFMA -> D^T per-lane:
// m = l16, n = quad*4+r (packed stores).
// MODE 0 (BM=128): Q (pre-scaled) / K -> [bh][t][d]; V -> Vt[bh][d][t].
// MODE 1 (BM=64): fp32 + bias via float4.
template<int BM, int MODE>
__launch_bounds__(256)
__global__ void k_gemm(const u16* __restrict__ A, const u16* __restrict__ Bt,
                       int M, int N, int K,
                       u16* __restrict__ Qb, u16* __restrict__ Kb, u16* __restrict__ Vt,
                       const float* __restrict__ bias, float* __restrict__ Cout) {
    constexpr int BN = 64, SM = BM / 32, SN = 2;
    __shared__ u16 Als[2][BM * 64];
    __shared__ u16 Bls[2][BN * 64];
    const int tid = threadIdx.x, lane = tid & 63, w = tid >> 6;
    const int quad = lane >> 4, l16 = lane & 15;
    const int sr = lane >> 3, sc = lane & 7;
    const int nt = N / BN;
    const int m0 = (blockIdx.x / nt) * BM, n0 = (blockIdx.x % nt) * BN;
    const int wm = (w >> 1) * (BM / 2), wn = (w & 1) * 32;

    auto stage = [&](int buf, int k0) {
        #pragma unroll
        for (int i = 0; i < BM / 32; ++i) {
            int rb = (w * (BM / 32) + i) * 8;
            gload16(&A[(long)(m0 + rb + sr) * K + k0 + ((sc ^ sr) << 3)], &Als[buf][rb * 64]);
        }
        #pragma unroll
        for (int i = 0; i < 2; ++i) {
            int rb = (w * 2 + i) * 8;
            gload16(&Bt[(long)(n0 + rb + sr) * K + k0 + ((sc ^ sr) << 3)], &Bls[buf][rb * 64]);
        }
    };

    floatx4 acc[SM][SN] = {};
    const int niter = K / 64;
    stage(0, 0);
    for (int it = 0; it < niter; ++it) {
        const int buf = it & 1;
        __syncthreads();                       // stage(it) visible + compute(it-1) done
        if (it + 1 < niter) stage(buf ^ 1, (it + 1) * 64);   // flies during compute
        bf16x8 af[SM][2], bfr[SN][2];
        #pragma unroll
        for (int sm = 0; sm < SM; ++sm) {
            int row = wm + sm * 16 + l16;
            #pragma unroll
            for (int ks = 0; ks < 2; ++ks)
                af[sm][ks] = *(const bf16x8*)&Als[buf][row * 64 + (((ks * 4 + quad) ^ (row & 7)) << 3)];
        }
        #pragma unroll
        for (int sn = 0; sn < SN; ++sn) {
            int row = wn + sn * 16 + l16;
            #pragma unroll
            for (int ks = 0; ks < 2; ++ks)
                bfr[sn][ks] = *(const bf16x8*)&Bls[buf][row * 64 + (((ks * 4 + quad) ^ (row & 7)) << 3)];
        }
        #pragma unroll
        for (int ks = 0; ks < 2; ++ks)
            #pragma unroll
            for (int sm = 0; sm < SM; ++sm)
                #pragma unroll
                for (int sn = 0; sn < SN; ++sn)
                    acc[sm][sn] = __builtin_amdgcn_mfma_f32_16x16x32_bf16(bfr[sn][ks], af[sm][ks], acc[sm][sn], 0, 0, 0);
    }
    if (MODE == 0) {
        const int qkv = n0 >> 10, h = (n0 & 1023) >> 6;     // uniform per block
        const float qs = qkv == 0 ? 0.18033688011112042f : 1.0f;  // log2(e)/sqrt(D)
        #pragma unroll
        for (int sm = 0; sm < SM; ++sm) {
            const int m = m0 + wm + sm * 16 + l16;
            const int bb = m >> 10, t = m & 1023;
            #pragma unroll
            for (int sn = 0; sn < SN; ++sn) {
                const int d0 = wn + sn * 16 + (quad << 2);
                u16 pk[4];
                #pragma unroll
                for (int r = 0; r < 4; ++r) pk[r] = f2bf(acc[sm][sn][r] * qs);
                if (qkv == 2) {
                    // direct V^T write: Vt[bh][d][t]; lanes share d, consecutive t
                    const long vb = (long)(bb * SH + h) * SD * ST + t;
                    #pragma unroll
                    for (int r = 0; r < 4; ++r) Vt[vb + (long)(d0 + r) * ST] = pk[r];
                } else {
                    u16* dst = qkv == 0 ? Qb : Kb;
                    *(uint2*)&dst[(((long)(bb * SH + h) * ST + t) << 6) + d0] = *(uint2*)pk;
                }
            }
        }
    } else {
        #pragma unroll
        for (int sn = 0; sn < SN; ++sn) {
            const int nb = n0 + wn + sn * 16 + (quad << 2);
            const float4 bv = *(const float4*)&bias[nb];
            #pragma unroll
            for (int sm = 0; sm < SM; ++sm) {
                const int m = m0 + wm + sm * 16 + l16;
                float4 o;
                o.x = acc[sm][sn][0] + bv.x;
                o.y = acc[sm][sn][1] + bv.y;
                o.z = acc[sm][sn][2] + bv.z;
                o.w = acc[sm][sn][3] + bv.w;
                *(float4*)&Cout[(long)m * N + nb] = o;
            }
        }
    }
}

// ---- flash attention: BARRIER-FREE. 64-row Q tile/block, 4 independent waves.
// K/V fragments loaded directly global->VGPR (tiles are L2-resident: same-bh
// blocks share an XCD via blockIdx%8). P bounce stays in wave-private LDS.
// kf(j+1) prefetched during exp/PV of j; vf(j) issued before the exp block.
// Swapped-operand MFMA (S^T: s = quad*4+r, t = l16) -> per-lane scalar row sum.
__launch_bounds__(256)
__global__ void k_attn(const u16* __restrict__ Qg, const u16* __restrict__ Kg,
                       const u16* __restrict__ Vtg, u16* __restrict__ Og) {
    __shared__ u16 Pls[64 * 64];      // P [t_local][s], per-wave 16-row slices
    const int tid = threadIdx.x, lane = tid & 63, w = tid >> 6;
    const int quad = lane >> 4, l16 = lane & 15;
    const int tile = 15 - (blockIdx.x >> 6);       // longest tiles dispatch first
    const int bh = blockIdx.x & 63;                // same-bh blocks -> same XCD class
    const int t0 = tile * 64;
    const int b = bh >> 4, h = bh & 15;
    const u16* Qbh = Qg + (long)bh * ST * SD;
    const u16* Kbh = Kg + (long)bh * ST * SD;      // [t][d]
    const u16* Vbh = Vtg + (long)bh * SD * ST;     // [d][t]

    bf16x8 qf[2];
    {
        const u16* qrow = Qbh + (t0 + w * 16 + l16) * SD;
        qf[0] = *(const bf16x8*)&qrow[quad * 8];
        qf[1] = *(const bf16x8*)&qrow[32 + quad * 8];
    }
    floatx4 oacc[4] = {};
    float lsum = 0.f;
    const int myt = t0 + w * 16 + l16;             // this lane's global t row
    const int rowP = w * 16 + l16;                 // P row (wave-private)

    // K frag addresses: row sn*16+l16 of tile j, cols ks*32+quad*8
    const u16* kbase = Kbh + (long)l16 * SD + quad * 8;
    const u16* vbase = Vbh + (long)l16 * ST + quad * 8;

    bf16x8 kf[4][2];
    #pragma unroll
    for (int sn = 0; sn < 4; ++sn)
        #pragma unroll
        for (int ks = 0; ks < 2; ++ks)
            kf[sn][ks] = *(const bf16x8*)&kbase[(long)sn * 16 * SD + ks * 32];

    for (int j = 0; j <= tile; ++j) {
        const int s0 = j * 64;
        // S^T = (Q K^T)^T : mfma(K-frag, Q-frag) -> s = quad*4+r, t = l16
        floatx4 sa[4] = {};
        #pragma unroll
        for (int sn = 0; sn < 4; ++sn) {
            sa[sn] = __builtin_amdgcn_mfma_f32_16x16x32_bf16(kf[sn][0], qf[0], sa[sn], 0, 0, 0);
            sa[sn] = __builtin_amdgcn_mfma_f32_16x16x32_bf16(kf[sn][1], qf[1], sa[sn], 0, 0, 0);
        }
        // issue V(j) loads now: they fly during the exp/P phase
        bf16x8 vf[4][2];
        #pragma unroll
        for (int dn = 0; dn < 4; ++dn)
            #pragma unroll
            for (int ks = 0; ks < 2; ++ks)
                vf[dn][ks] = *(const bf16x8*)&vbase[(long)dn * 16 * ST + s0 + ks * 32];
        // prefetch K(j+1): covered by exp/P/PV phases
        if (j < tile) {
            #pragma unroll
            for (int sn = 0; sn < 4; ++sn)
                #pragma unroll
                for (int ks = 0; ks < 2; ++ks)
                    kf[sn][ks] = *(const bf16x8*)&kbase[(long)(s0 + 64 + sn * 16) * SD + ks * 32];
        }
        const bool diag = (j == tile);
        #pragma unroll
        for (int sn = 0; sn < 4; ++sn) {
            const int sl = sn * 16 + (quad << 2);
            u16 pk[4];
            #pragma unroll
            for (int r = 0; r < 4; ++r) {
                float e = __builtin_exp2f(sa[sn][r]);
                if (diag && s0 + sl + r > myt) e = 0.f;
                lsum += e;
                pk[r] = (u16)(__builtin_bit_cast(unsigned int, e) >> 16);  // trunc, e>=0
            }
            *(uint2*)&Pls[rowP * 64 + (((sl >> 3) ^ (rowP & 7)) << 3) + ((quad & 1) << 2)] = *(uint2*)pk;
        }
        // P rows wave-private: lgkmcnt covers RAW, no barrier
        bf16x8 pf[2];
        #pragma unroll
        for (int ks = 0; ks < 2; ++ks)
            pf[ks] = *(const bf16x8*)&Pls[rowP * 64 + (((ks * 4 + quad) ^ (rowP & 7)) << 3)];
        // O^T += (P V)^T : mfma(Vt-frag, P-frag) -> d = quad*4+r, t = l16
        #pragma unroll
        for (int dn = 0; dn < 4; ++dn) {
            oacc[dn] = __builtin_amdgcn_mfma_f32_16x16x32_bf16(vf[dn][0], pf[0], oacc[dn], 0, 0, 0);
            oacc[dn] = __builtin_amdgcn_mfma_f32_16x16x32_bf16(vf[dn][1], pf[1], oacc[dn], 0, 0, 0);
        }
    }
    // per-lane row sum: reduce the 4 quads (same t = l16)
    float l = lsum;
    l += __shfl_xor(l, 16);
    l += __shfl_xor(l, 32);
    const float inv = 1.0f / l;
    const long obase = ((long)(b * ST + myt) << 10) + h * SD;
    #pragma unroll
    for (int dn = 0; dn < 4; ++dn) {
        u16 pk[4];
        #pragma unroll
        for (int r = 0; r < 4; ++r) pk[r] = f2bf(oacc[dn][r] * inv);
        *(uint2*)&Og[obase + dn * 16 + (quad << 2)] = *(uint2*)pk;
    }
}

extern "C" void kernel_launch(void* const* d_in, const int* in_sizes, int n_in,
                              void* d_out, int out_size, void* d_ws, size_t ws_size,
                              hipStream_t stream) {
    const float* x  = (const float*)d_in[0];
    const float* Wq = (const float*)d_in[1];
    const float* Wk = (const float*)d_in[2];
    const float* Wv = (const float*)d_in[3];
    const float* Wp = (const float*)d_in[4];
    const float* bp = (const float*)d_in[5];
    float* out = (float*)d_out;

    char* ws = (char*)d_ws;                       // 48 MB used
    u16* xb   = (u16*)(ws);                       // [4096][1024]   8 MB
    u16* Wqkv = (u16*)(ws + (8ll  << 20));        // [3072][1024]   6 MB
    u16* Wpt  = (u16*)(ws + (14ll << 20));        // [1024][1024]   2 MB
    u16* Qb   = (u16*)(ws + (16ll << 20));        // [64][1024][64] 8 MB
    u16* Kb   = (u16*)(ws + (24ll << 20));        // 8 MB
    u16* Vt   = (u16*)(ws + (32ll << 20));        // [64][64][1024] 8 MB
    u16* Ob   = (u16*)(ws + (40ll << 20));        // [4096][1024]   8 MB

    // fused conversions: 4096 (x) + 768 (Wqkv) + 256 (Wp) blocks
    k_prep<<<5120, 256, 0, stream>>>(x, Wq, Wk, Wv, Wp, xb, Wqkv, Wpt);
    // QKV projection: M=4096 N=3072 K=1024, 128x64 tiles -> 1536 blocks
    k_gemm<128, 0><<<32 * 48, 256, 0, stream>>>(xb, Wqkv, 4096, 3072, 1024, Qb, Kb, Vt, nullptr, nullptr);
    // attention: 1024 blocks, longest-first, barrier-free
    k_attn<<<1024, 256, 0, stream>>>(Qb, Kb, Vt, Ob);
    // output projection: M=4096 N=1024 K=1024 (+bias), 64x64 tiles -> 1024 blocks
    k_gemm<64, 1><<<64 * 16, 256, 0, stream>>>(Ob, Wpt, 4096, 1024, 1024, nullptr, nullptr, nullptr, bp, out);
}

// Round 7
// 161.073 us; speedup vs baseline: 1.2766x; 1.2766x over previous
//
#include <hip/hip_runtime.h>
#include <hip/hip_bf16.h>

typedef unsigned short u16;
typedef __bf16 bf16x8 __attribute__((ext_vector_type(8)));
typedef float floatx4 __attribute__((ext_vector_type(4)));

#define SB 4
#define ST 1024
#define SC 1024
#define SH 16
#define SD 64

__device__ __forceinline__ u16 f2bf(float f) {
    unsigned int u = __builtin_bit_cast(unsigned int, f);
    u += 0x7fffu + ((u >> 16) & 1u);   // RNE
    return (u16)(u >> 16);
}

// async 16B/lane global->LDS (m97). LDS dest is wave-uniform base + lane*16.
__device__ __forceinline__ void gload16(const u16* g, u16* l) {
    __builtin_amdgcn_global_load_lds(
        (const __attribute__((address_space(1))) unsigned int*)g,
        (__attribute__((address_space(3))) unsigned int*)l, 16, 0, 0);
}

// ---- fused prep: x->bf16 | Wq/Wk/Wv -> Wqkv[n][c] | Wp -> Wpt[n][k] ----
__global__ void k_prep(const float* __restrict__ x,
                       const float* __restrict__ Wq, const float* __restrict__ Wk,
                       const float* __restrict__ Wv, const float* __restrict__ Wp,
                       u16* __restrict__ xb, u16* __restrict__ Wqkv, u16* __restrict__ Wpt) {
    __shared__ float tile[64 * 65];
    const int id = blockIdx.x, tid = threadIdx.x;
    if (id < 4096) {                               // x: fp32 -> bf16, float4 lanes
        int i = id * 256 + tid;
        float4 v = ((const float4*)x)[i];
        uint2 o;
        o.x = (unsigned)f2bf(v.x) | ((unsigned)f2bf(v.y) << 16);
        o.y = (unsigned)f2bf(v.z) | ((unsigned)f2bf(v.w) << 16);
        ((uint2*)xb)[i] = o;
    } else if (id < 4864) {                        // Wq/Wk/Wv transpose to [n][c]
        const int id1 = id - 4096;
        const int qkv = id1 >> 8, rem = id1 & 255, h = rem >> 4, c0 = (rem & 15) * 64;
        const float* src = qkv == 0 ? Wq : (qkv == 1 ? Wk : Wv);
        #pragma unroll
        for (int i = 0; i < 16; ++i) {
            int idx = tid + i * 256;
            int r = idx >> 6, d = idx & 63;
            tile[r * 65 + d] = src[(h * SC + c0 + r) * SD + d];
        }
        __syncthreads();
        #pragma unroll
        for (int i = 0; i < 16; ++i) {
            int idx = tid + i * 256;
            int d = idx >> 6, cc = idx & 63;
            Wqkv[(qkv * 1024 + h * SD + d) * SC + c0 + cc] = f2bf(tile[cc * 65 + d]);
        }
    } else {                                       // Wp transpose to [n][k]
        const int id2 = id - 4864;
        const int n0 = (id2 & 15) * 64, k0 = (id2 >> 4) * 64;
        #pragma unroll
        for (int i = 0; i < 16; ++i) {
            int idx = tid + i * 256;
            int r = idx >> 6, nn = idx & 63;
            tile[r * 65 + nn] = Wp[(k0 + r) * SC + n0 + nn];
        }
        __syncthreads();
        #pragma unroll
        for (int i = 0; i < 16; ++i) {
            int idx = tid + i * 256;
            int nr = idx >> 6, kk = idx & 63;
            Wpt[(n0 + nr) * (SH * SD) + k0 + kk] = f2bf(tile[kk * 65 + nr]);
        }
    }
}

// ---- QKV GEMM: C = A[M,K] * Bt[N,K]^T, bf16, BM=128, BN=64, BK=64 ----
// Single-barrier prefetch double-buffer. Swapped-operand MFMA -> D^T per-lane:
// m = l16, n = quad*4+r (packed stores).
// Q (pre-scaled by log2e/8) / K -> [bh][t][d]; V -> Vt[bh][d][t].
__launch_bounds__(256)
__global__ void k_gemm(const u16* __restrict__ A, const u16* __restrict__ Bt,
                       int M, int N, int K,
                       u16* __restrict__ Qb, u16* __restrict__ Kb, u16* __restrict__ Vt) {
    constexpr int BM = 128, BN = 64, SM = 4, SN = 2;
    __shared__ u16 Als[2][BM * 64];
    __shared__ u16 Bls[2][BN * 64];
    const int tid = threadIdx.x, lane = tid & 63, w = tid >> 6;
    const int quad = lane >> 4, l16 = lane & 15;
    const int sr = lane >> 3, sc = lane & 7;
    const int nt = N / BN;
    const int m0 = (blockIdx.x / nt) * BM, n0 = (blockIdx.x % nt) * BN;
    const int wm = (w >> 1) * 64, wn = (w & 1) * 32;

    auto stage = [&](int buf, int k0) {
        #pragma unroll
        for (int i = 0; i < 4; ++i) {
            int rb = (w * 4 + i) * 8;
            gload16(&A[(long)(m0 + rb + sr) * K + k0 + ((sc ^ sr) << 3)], &Als[buf][rb * 64]);
        }
        #pragma unroll
        for (int i = 0; i < 2; ++i) {
            int rb = (w * 2 + i) * 8;
            gload16(&Bt[(long)(n0 + rb + sr) * K + k0 + ((sc ^ sr) << 3)], &Bls[buf][rb * 64]);
        }
    };

    floatx4 acc[SM][SN] = {};
    const int niter = K / 64;
    stage(0, 0);
    for (int it = 0; it < niter; ++it) {
        const int buf = it & 1;
        __syncthreads();                       // stage(it) visible + compute(it-1) done
        if (it + 1 < niter) stage(buf ^ 1, (it + 1) * 64);   // flies during compute
        bf16x8 af[SM][2], bfr[SN][2];
        #pragma unroll
        for (int sm = 0; sm < SM; ++sm) {
            int row = wm + sm * 16 + l16;
            #pragma unroll
            for (int ks = 0; ks < 2; ++ks)
                af[sm][ks] = *(const bf16x8*)&Als[buf][row * 64 + (((ks * 4 + quad) ^ (row & 7)) << 3)];
        }
        #pragma unroll
        for (int sn = 0; sn < SN; ++sn) {
            int row = wn + sn * 16 + l16;
            #pragma unroll
            for (int ks = 0; ks < 2; ++ks)
                bfr[sn][ks] = *(const bf16x8*)&Bls[buf][row * 64 + (((ks * 4 + quad) ^ (row & 7)) << 3)];
        }
        #pragma unroll
        for (int ks = 0; ks < 2; ++ks)
            #pragma unroll
            for (int sm = 0; sm < SM; ++sm)
                #pragma unroll
                for (int sn = 0; sn < SN; ++sn)
                    acc[sm][sn] = __builtin_amdgcn_mfma_f32_16x16x32_bf16(bfr[sn][ks], af[sm][ks], acc[sm][sn], 0, 0, 0);
    }
    const int qkv = n0 >> 10, h = (n0 & 1023) >> 6;     // uniform per block
    const float qs = qkv == 0 ? 0.18033688011112042f : 1.0f;  // log2(e)/sqrt(D)
    #pragma unroll
    for (int sm = 0; sm < SM; ++sm) {
        const int m = m0 + wm + sm * 16 + l16;
        const int bb = m >> 10, t = m & 1023;
        #pragma unroll
        for (int sn = 0; sn < SN; ++sn) {
            const int d0 = wn + sn * 16 + (quad << 2);
            u16 pk[4];
            #pragma unroll
            for (int r = 0; r < 4; ++r) pk[r] = f2bf(acc[sm][sn][r] * qs);
            if (qkv == 2) {
                // direct V^T write: Vt[bh][d][t]; lanes share d, consecutive t
                const long vb = (long)(bb * SH + h) * SD * ST + t;
                #pragma unroll
                for (int r = 0; r < 4; ++r) Vt[vb + (long)(d0 + r) * ST] = pk[r];
            } else {
                u16* dst = qkv == 0 ? Qb : Kb;
                *(uint2*)&dst[(((long)(bb * SH + h) * ST + t) << 6) + d0] = *(uint2*)pk;
            }
        }
    }
}

// ---- out-projection: C[4096,1024] = Ob * Wpt^T + bias, BM=BN=64, BK=256 ----
// BK=256 staged as 4 x 64-k sub-tiles (contiguous global_load_lds), single
// buffer: 8 barriers total (vs 32 at BK=64), 32 MFMA/wave per interval.
__launch_bounds__(256)
__global__ void k_oproj(const u16* __restrict__ A, const u16* __restrict__ Bt,
                        const float* __restrict__ bias, float* __restrict__ Cout) {
    constexpr int K = 1024, N = 1024;
    __shared__ u16 Als[4][64 * 64];
    __shared__ u16 Bls[4][64 * 64];
    const int tid = threadIdx.x, lane = tid & 63, w = tid >> 6;
    const int quad = lane >> 4, l16 = lane & 15;
    const int sr = lane >> 3, sc = lane & 7;
    const int m0 = (blockIdx.x >> 4) * 64, n0 = (blockIdx.x & 15) * 64;
    const int wm = (w >> 1) * 32, wn = (w & 1) * 32;

    floatx4 acc[2][2] = {};
    for (int kb = 0; kb < 4; ++kb) {
        const int k0 = kb * 256;
        #pragma unroll
        for (int seg = 0; seg < 4; ++seg) {
            #pragma unroll
            for (int i = 0; i < 2; ++i) {
                int rb = (w * 2 + i) * 8;
                gload16(&A[(long)(m0 + rb + sr) * K + k0 + seg * 64 + ((sc ^ sr) << 3)], &Als[seg][rb * 64]);
                gload16(&Bt[(long)(n0 + rb + sr) * K + k0 + seg * 64 + ((sc ^ sr) << 3)], &Bls[seg][rb * 64]);
            }
        }
        __syncthreads();
        #pragma unroll
        for (int seg = 0; seg < 4; ++seg) {
            bf16x8 af[2][2], bfr[2][2];
            #pragma unroll
            for (int sm = 0; sm < 2; ++sm) {
                int row = wm + sm * 16 + l16;
                #pragma unroll
                for (int ks = 0; ks < 2; ++ks)
                    af[sm][ks] = *(const bf16x8*)&Als[seg][row * 64 + (((ks * 4 + quad) ^ (row & 7)) << 3)];
            }
            #pragma unroll
            for (int sn = 0; sn < 2; ++sn) {
                int row = wn + sn * 16 + l16;
                #pragma unroll
                for (int ks = 0; ks < 2; ++ks)
                    bfr[sn][ks] = *(const bf16x8*)&Bls[seg][row * 64 + (((ks * 4 + quad) ^ (row & 7)) << 3)];
            }
            #pragma unroll
            for (int ks = 0; ks < 2; ++ks)
                #pragma unroll
                for (int sm = 0; sm < 2; ++sm)
                    #pragma unroll
                    for (int sn = 0; sn < 2; ++sn)
                        acc[sm][sn] = __builtin_amdgcn_mfma_f32_16x16x32_bf16(bfr[sn][ks], af[sm][ks], acc[sm][sn], 0, 0, 0);
        }
        if (kb < 3) __syncthreads();           // protect LDS before next stage
    }
    #pragma unroll
    for (int sn = 0; sn < 2; ++sn) {
        const int nb = n0 + wn + sn * 16 + (quad << 2);
        const float4 bv = *(const float4*)&bias[nb];
        #pragma unroll
        for (int sm = 0; sm < 2; ++sm) {
            const int m = m0 + wm + sm * 16 + l16;
            float4 o;
            o.x = acc[sm][sn][0] + bv.x;
            o.y = acc[sm][sn][1] + bv.y;
            o.z = acc[sm][sn][2] + bv.z;
            o.w = acc[sm][sn][3] + bv.w;
            *(float4*)&Cout[(long)m * N + nb] = o;
        }
    }
}

// ---- flash attention: 64-row Q tile/block, prefetch double-buffered K/V ----
// (round-5 version — LDS cooperative staging beats per-wave VGPR loads)
__launch_bounds__(256)
__global__ void k_attn(const u16* __restrict__ Qg, const u16* __restrict__ Kg,
                       const u16* __restrict__ Vtg, u16* __restrict__ Og) {
    __shared__ u16 Kls[2][64 * 64];   // K tile [s][d], XOR-swizzled chunks
    __shared__ u16 Vls[2][64 * 64];   // Vt tile [d][s], XOR-swizzled chunks
    __shared__ u16 Pls[64 * 64];      // P [t_local][s], per-wave 16-row slices
    const int tid = threadIdx.x, lane = tid & 63, w = tid >> 6;
    const int quad = lane >> 4, l16 = lane & 15;
    const int sr = lane >> 3, sc = lane & 7;
    const int tile = 15 - (blockIdx.x >> 6);       // longest tiles dispatch first
    const int bh = blockIdx.x & 63;
    const int t0 = tile * 64;
    const int b = bh >> 4, h = bh & 15;
    const u16* Qbh = Qg + (long)bh * ST * SD;
    const u16* Kbh = Kg + (long)bh * ST * SD;
    const u16* Vbh = Vtg + (long)bh * SD * ST;     // [d][t]

    bf16x8 qf[2];
    {
        const u16* qrow = Qbh + (t0 + w * 16 + l16) * SD;
        qf[0] = *(const bf16x8*)&qrow[quad * 8];
        qf[1] = *(const bf16x8*)&qrow[32 + quad * 8];
    }
    floatx4 oacc[4] = {};
    float lsum = 0.f;
    const int myt = t0 + w * 16 + l16;             // this lane's global t row
    const int rowP = w * 16 + l16;                 // P row (wave-private)

    auto stage = [&](int buf, int s0) {
        #pragma unroll
        for (int i = 0; i < 2; ++i) {
            int rb = (w * 2 + i) * 8;
            gload16(&Kbh[(s0 + rb + sr) * SD + ((sc ^ sr) << 3)], &Kls[buf][rb * 64]);
            gload16(&Vbh[(rb + sr) * ST + s0 + ((sc ^ sr) << 3)], &Vls[buf][rb * 64]);
        }
    };

    stage(0, 0);
    for (int j = 0; j <= tile; ++j) {
        const int buf = j & 1;
        const int s0 = j * 64;
        __syncthreads();                           // stage(j) visible + compute(j-1) done
        if (j < tile) stage(buf ^ 1, s0 + 64);     // flies during compute

        // S^T = (Q K^T)^T : mfma(K-frag, Q-frag) -> s = quad*4+r, t = l16
        floatx4 sa[4] = {};
        #pragma unroll
        for (int sn = 0; sn < 4; ++sn) {
            int row = sn * 16 + l16;
            #pragma unroll
            for (int ks = 0; ks < 2; ++ks) {
                bf16x8 kf = *(const bf16x8*)&Kls[buf][row * 64 + (((ks * 4 + quad) ^ (row & 7)) << 3)];
                sa[sn] = __builtin_amdgcn_mfma_f32_16x16x32_bf16(kf, qf[ks], sa[sn], 0, 0, 0);
            }
        }
        const bool diag = (j == tile);
        #pragma unroll
        for (int sn = 0; sn < 4; ++sn) {
            const int sl = sn * 16 + (quad << 2);
            u16 pk[4];
            #pragma unroll
            for (int r = 0; r < 4; ++r) {
                float e = __builtin_exp2f(sa[sn][r]);
                if (diag && s0 + sl + r > myt) e = 0.f;
                lsum += e;
                pk[r] = (u16)(__builtin_bit_cast(unsigned int, e) >> 16);  // trunc, e>=0
            }
            *(uint2*)&Pls[rowP * 64 + (((sl >> 3) ^ (rowP & 7)) << 3) + ((quad & 1) << 2)] = *(uint2*)pk;
        }
        // P rows wave-private: lgkmcnt covers RAW, no barrier
        bf16x8 pf[2];
        #pragma unroll
        for (int ks = 0; ks < 2; ++ks)
            pf[ks] = *(const bf16x8*)&Pls[rowP * 64 + (((ks * 4 + quad) ^ (rowP & 7)) << 3)];
        // O^T += (P V)^T : mfma(Vt-frag, P-frag) -> d = quad*4+r, t = l16
        #pragma unroll
        for (int dn = 0; dn < 4; ++dn) {
            int row = dn * 16 + l16;
            #pragma unroll
            for (int ks = 0; ks < 2; ++ks) {
                bf16x8 vf = *(const bf16x8*)&Vls[buf][row * 64 + (((ks * 4 + quad) ^ (row & 7)) << 3)];
                oacc[dn] = __builtin_amdgcn_mfma_f32_16x16x32_bf16(vf, pf[ks], oacc[dn], 0, 0, 0);
            }
        }
    }
    // per-lane row sum: reduce the 4 quads (same t = l16)
    float l = lsum;
    l += __shfl_xor(l, 16);
    l += __shfl_xor(l, 32);
    const float inv = 1.0f / l;
    const long obase = ((long)(b * ST + myt) << 10) + h * SD;
    #pragma unroll
    for (int dn = 0; dn < 4; ++dn) {
        u16 pk[4];
        #pragma unroll
        for (int r = 0; r < 4; ++r) pk[r] = f2bf(oacc[dn][r] * inv);
        *(uint2*)&Og[obase + dn * 16 + (quad << 2)] = *(uint2*)pk;
    }
}

extern "C" void kernel_launch(void* const* d_in, const int* in_sizes, int n_in,
                              void* d_out, int out_size, void* d_ws, size_t ws_size,
                              hipStream_t stream) {
    const float* x  = (const float*)d_in[0];
    const float* Wq = (const float*)d_in[1];
    const float* Wk = (const float*)d_in[2];
    const float* Wv = (const float*)d_in[3];
    const float* Wp = (const float*)d_in[4];
    const float* bp = (const float*)d_in[5];
    float* out = (float*)d_out;

    char* ws = (char*)d_ws;                       // 48 MB used
    u16* xb   = (u16*)(ws);                       // [4096][1024]   8 MB
    u16* Wqkv = (u16*)(ws + (8ll  << 20));        // [3072][1024]   6 MB
    u16* Wpt  = (u16*)(ws + (14ll << 20));        // [1024][1024]   2 MB
    u16* Qb   = (u16*)(ws + (16ll << 20));        // [64][1024][64] 8 MB
    u16* Kb   = (u16*)(ws + (24ll << 20));        // 8 MB
    u16* Vt   = (u16*)(ws + (32ll << 20));        // [64][64][1024] 8 MB
    u16* Ob   = (u16*)(ws + (40ll << 20));        // [4096][1024]   8 MB

    // fused conversions: 4096 (x) + 768 (Wqkv) + 256 (Wp) blocks
    k_prep<<<5120, 256, 0, stream>>>(x, Wq, Wk, Wv, Wp, xb, Wqkv, Wpt);
    // QKV projection: M=4096 N=3072 K=1024, 128x64 tiles -> 1536 blocks
    k_gemm<<<32 * 48, 256, 0, stream>>>(xb, Wqkv, 4096, 3072, 1024, Qb, Kb, Vt);
    // attention: 1024 blocks, longest-first (round-5 LDS-staged version)
    k_attn<<<1024, 256, 0, stream>>>(Qb, Kb, Vt, Ob);
    // output projection: 64x64 tiles, BK=256 -> 1024 blocks, 8 barriers
    k_oproj<<<1024, 256, 0, stream>>>(Ob, Wpt, bp, out);
}